// Round 1
// baseline (500.983 us; speedup 1.0000x reference)
//
#include <hip/hip_runtime.h>

// IndRNN recurrence: h_t = relu(h_{t-1} * w + x_t), elementwise over (B,H),
// sequential over T.
//
// R2: the single-pass kernel ran at 1.26 TB/s (427 us) vs 6.3 TB/s memset on
// the same chip: latency-bound, not BW-bound. BH/256 = 256 blocks = 1
// wave/SIMD -> zero TLP; each 16-step prefetch window burst-drains (~16k cyc
// per window measured).
//
// Fix: exact chunk-parallel decomposition. relu(w*h+x) = max(w*h+x, 0) is
// max-affine in h; the family g(h) = max(A*h+B, C) is closed under
// composition: A'=wA, B'=wB+x, C'=max(wC+x,0). So:
//   pass 1: per chunk (8 chunks of 128 steps), accumulate (B,C). A = w^128.
//   pass 3: per chunk, replay the <=7-step boundary chain from (A,B,C) to get
//           the exact chunk-start h, then run the recurrence as before.
// All fp32, same op order inside chunks -> diff vs reference is fp32 path
// noise (~1e-4). C is initialized to 0 instead of -inf: valid because every
// chunk-start h >= 0 (h0 = 0, and max(.,C>=0) >= 0), and g is monotone.
//
// Occupancy: pass 3 = 8 chunks * 16384 float4-threads = 512 blocks = 32
// waves/CU (was 4). float4 loads (16 B/lane). W=8 float4 prefetch window =
// 8 KB/wave in flight, 64 KB/CU >> 9 KB Little's-law requirement.
// Traffic: 256 MiB (pass1 rd) + 4 MiB + 256+15 MiB rd + 256 MiB wr
// ~= 780 MiB -> floor ~124 us at 6.3 TB/s. Predict 150-180 us.

#define T_DIM 1024
#define B_DIM 64
#define H_DIM 1024
#define BH  (B_DIM * H_DIM)   // 65536
#define BH4 (BH / 4)          // 16384 float4 lanes
#define H4  (H_DIM / 4)       // 256
#define NC  8                 // chunks over T
#define TC  (T_DIM / NC)      // 128 steps per chunk
#define W   8                 // float4 prefetch window

__device__ __forceinline__ float4 relu_step(float4 h, float4 wv, float4 xv) {
    float4 r;
    r.x = fmaxf(fmaf(h.x, wv.x, xv.x), 0.0f);
    r.y = fmaxf(fmaf(h.y, wv.y, xv.y), 0.0f);
    r.z = fmaxf(fmaf(h.z, wv.z, xv.z), 0.0f);
    r.w = fmaxf(fmaf(h.w, wv.w, xv.w), 0.0f);
    return r;
}

// Pass 1: per-chunk composed (B, C). One thread per (chunk, 4 elems of BH).
__global__ __launch_bounds__(256) void indrnn_compose(
    const float* __restrict__ x,
    const float* __restrict__ w,
    float* __restrict__ Bws,          // [NC][BH]
    float* __restrict__ Cws)          // [NC][BH]
{
    const int g  = blockIdx.x * 256 + threadIdx.x;   // NC * BH4 threads
    const int c  = g >> 14;                          // / BH4
    const int i4 = g & (BH4 - 1);
    const float4  wv = reinterpret_cast<const float4*>(w)[i4 & (H4 - 1)];
    const float4* xp = reinterpret_cast<const float4*>(x) + (size_t)c * TC * BH4 + i4;

    float4 Bv = make_float4(0.f, 0.f, 0.f, 0.f);
    float4 Cv = make_float4(0.f, 0.f, 0.f, 0.f);

    float4 buf[W];
    #pragma unroll
    for (int i = 0; i < W; ++i) buf[i] = xp[(size_t)i * BH4];

    for (int t0 = 0; t0 < TC; t0 += W) {
        const int tp = (t0 + W < TC) ? (t0 + W) : 0;  // tail re-reads win 0 (dead)
        float4 nbuf[W];
        #pragma unroll
        for (int i = 0; i < W; ++i) nbuf[i] = xp[(size_t)(tp + i) * BH4];

        #pragma unroll
        for (int i = 0; i < W; ++i) {
            const float4 xv = buf[i];
            Bv.x = fmaf(Bv.x, wv.x, xv.x);
            Bv.y = fmaf(Bv.y, wv.y, xv.y);
            Bv.z = fmaf(Bv.z, wv.z, xv.z);
            Bv.w = fmaf(Bv.w, wv.w, xv.w);
            Cv = relu_step(Cv, wv, xv);
        }
        #pragma unroll
        for (int i = 0; i < W; ++i) buf[i] = nbuf[i];
    }
    reinterpret_cast<float4*>(Bws)[(size_t)c * BH4 + i4] = Bv;
    reinterpret_cast<float4*>(Cws)[(size_t)c * BH4 + i4] = Cv;
}

// Pass 3: boundary chain from composed (A,B,C), then in-chunk recurrence.
__global__ __launch_bounds__(256) void indrnn_run(
    const float* __restrict__ x,
    const float* __restrict__ w,
    const float* __restrict__ h0,
    const float* __restrict__ Bws,
    const float* __restrict__ Cws,
    float* __restrict__ out)
{
    const int g  = blockIdx.x * 256 + threadIdx.x;   // NC * BH4 threads
    const int c  = g >> 14;                          // uniform per block
    const int i4 = g & (BH4 - 1);
    const float4 wv = reinterpret_cast<const float4*>(w)[i4 & (H4 - 1)];

    float4 h = reinterpret_cast<const float4*>(h0)[i4];

    // A = w^TC = w^128 via 7 squarings
    float4 A = wv;
    #pragma unroll
    for (int k = 0; k < 7; ++k) {
        A.x *= A.x; A.y *= A.y; A.z *= A.z; A.w *= A.w;
    }
    // exact boundary chain: h -> chunk-start h for chunk c
    for (int cc = 0; cc < c; ++cc) {
        const float4 Bv = reinterpret_cast<const float4*>(Bws)[(size_t)cc * BH4 + i4];
        const float4 Cv = reinterpret_cast<const float4*>(Cws)[(size_t)cc * BH4 + i4];
        h.x = fmaxf(fmaf(A.x, h.x, Bv.x), Cv.x);
        h.y = fmaxf(fmaf(A.y, h.y, Bv.y), Cv.y);
        h.z = fmaxf(fmaf(A.z, h.z, Bv.z), Cv.z);
        h.w = fmaxf(fmaf(A.w, h.w, Bv.w), Cv.w);
    }

    const float4* xp = reinterpret_cast<const float4*>(x)   + (size_t)c * TC * BH4 + i4;
    float4*       op = reinterpret_cast<float4*>(out)       + (size_t)c * TC * BH4 + i4;

    float4 buf[W];
    #pragma unroll
    for (int i = 0; i < W; ++i) buf[i] = xp[(size_t)i * BH4];

    for (int t0 = 0; t0 < TC; t0 += W) {
        const int tp = (t0 + W < TC) ? (t0 + W) : 0;
        float4 nbuf[W];
        #pragma unroll
        for (int i = 0; i < W; ++i) nbuf[i] = xp[(size_t)(tp + i) * BH4];

        #pragma unroll
        for (int i = 0; i < W; ++i) {
            h = relu_step(h, wv, buf[i]);
            op[(size_t)(t0 + i) * BH4] = h;
        }
        #pragma unroll
        for (int i = 0; i < W; ++i) buf[i] = nbuf[i];
    }
}

extern "C" void kernel_launch(void* const* d_in, const int* in_sizes, int n_in,
                              void* d_out, int out_size, void* d_ws, size_t ws_size,
                              hipStream_t stream) {
    const float* x  = (const float*)d_in[0];
    const float* w  = (const float*)d_in[1];
    const float* h0 = (const float*)d_in[2];
    float* out = (float*)d_out;

    // workspace: Bws [NC][BH] + Cws [NC][BH] = 4 MiB
    float* Bws = (float*)d_ws;
    float* Cws = Bws + (size_t)NC * BH;

    indrnn_compose<<<NC * BH4 / 256, 256, 0, stream>>>(x, w, Bws, Cws);
    indrnn_run<<<NC * BH4 / 256, 256, 0, stream>>>(x, w, h0, Bws, Cws, out);
}

// Round 3
// 495.218 us; speedup vs baseline: 1.0116x; 1.0116x over previous
//
#include <hip/hip_runtime.h>

// IndRNN recurrence: h_t = relu(h_{t-1} * w + x_t), elementwise over (B,H),
// sequential over T.
//
// R4 = R3 with the compile fix: __builtin_nontemporal_store needs a native
// clang vector type, not HIP's float4 class. Cast through ext_vector_type(4).
//
// R3 theory (unchanged): R2 (8 chunks, 8 waves/CU) ran both passes at the
// same ~1.5 TB/s stream BW as R0 -> 501 us. The t-walk (256 KiB stride,
// small bursts) is DRAM row-activate unfriendly; BW scaled with stream count
// (R0->R2: 2x streams -> +27%), so R3/R4 maxes request-level parallelism:
//  - NC=32 chunks (TC=32): 2048 blocks, ~24 waves/CU in streaming passes.
//  - Boundary chain in its own tiny pass-2 kernel (24 MiB, cache-hot).
//  - Nontemporal stores for out (never re-read; keeps L2/L3 for x).
//
// Math (exact): relu(w*h+x) = max(w*h+x,0) is max-affine in h; g(h) =
// max(A*h+B, C) composes as A'=wA, B'=wB+x, C'=max(wC+x,0). C init 0 valid
// for h>=0. Shorter chunks (32) -> composition error <= R2's 0.25 (passed).
//
// Traffic: pass1 rd 256 + wr 16 MiB; pass2 ~24 MiB hot; pass3 rd 264 + wr
// 256 MiB. Floor ~127 us at 6.3 TB/s. Predict 200-280 us at 3-5 TB/s;
// >=400 us falsifies the parallelism lever -> layout restructure next.

#define T_DIM 1024
#define B_DIM 64
#define H_DIM 1024
#define BH   (B_DIM * H_DIM)    // 65536
#define BH4  (BH / 4)           // 16384 float4 sites per t-slab
#define H4   (H_DIM / 4)        // 256
#define NC   32                 // chunks over T
#define TC   (T_DIM / NC)       // 32 steps per chunk
#define LOG2_BH4 14
#define W    4                  // float4 prefetch window

typedef float v4f __attribute__((ext_vector_type(4)));

__device__ __forceinline__ float4 relu_step(float4 h, float4 wv, float4 xv) {
    float4 r;
    r.x = fmaxf(fmaf(h.x, wv.x, xv.x), 0.0f);
    r.y = fmaxf(fmaf(h.y, wv.y, xv.y), 0.0f);
    r.z = fmaxf(fmaf(h.z, wv.z, xv.z), 0.0f);
    r.w = fmaxf(fmaf(h.w, wv.w, xv.w), 0.0f);
    return r;
}

__device__ __forceinline__ void nt_store4(float4* p, float4 v) {
    __builtin_nontemporal_store(*reinterpret_cast<const v4f*>(&v),
                                reinterpret_cast<v4f*>(p));
}

// Pass 1: per-chunk composed (B, C). One thread per (chunk, float4 site).
__global__ __launch_bounds__(256, 6) void indrnn_compose(
    const float* __restrict__ x,
    const float* __restrict__ w,
    float* __restrict__ Bws,          // [NC][BH]
    float* __restrict__ Cws)          // [NC][BH]
{
    const int g  = blockIdx.x * 256 + threadIdx.x;   // NC * BH4 threads
    const int c  = g >> LOG2_BH4;
    const int i4 = g & (BH4 - 1);
    const float4  wv = reinterpret_cast<const float4*>(w)[i4 & (H4 - 1)];
    const float4* xp = reinterpret_cast<const float4*>(x) + (size_t)c * TC * BH4 + i4;

    float4 Bv = make_float4(0.f, 0.f, 0.f, 0.f);
    float4 Cv = make_float4(0.f, 0.f, 0.f, 0.f);

    float4 buf[W];
    #pragma unroll
    for (int i = 0; i < W; ++i) buf[i] = xp[(size_t)i * BH4];

    for (int t0 = 0; t0 < TC; t0 += W) {
        const int tp = (t0 + W < TC) ? (t0 + W) : 0;  // tail re-reads win 0 (dead)
        float4 nbuf[W];
        #pragma unroll
        for (int i = 0; i < W; ++i) nbuf[i] = xp[(size_t)(tp + i) * BH4];

        #pragma unroll
        for (int i = 0; i < W; ++i) {
            const float4 xv = buf[i];
            Bv.x = fmaf(Bv.x, wv.x, xv.x);
            Bv.y = fmaf(Bv.y, wv.y, xv.y);
            Bv.z = fmaf(Bv.z, wv.z, xv.z);
            Bv.w = fmaf(Bv.w, wv.w, xv.w);
            Cv = relu_step(Cv, wv, xv);
        }
        #pragma unroll
        for (int i = 0; i < W; ++i) buf[i] = nbuf[i];
    }
    reinterpret_cast<float4*>(Bws)[(size_t)c * BH4 + i4] = Bv;
    reinterpret_cast<float4*>(Cws)[(size_t)c * BH4 + i4] = Cv;
}

// Pass 2: serial scan over chunks -> exact chunk-start h for every chunk.
// 16K threads; reads/writes 24 MiB, all L2/L3-hot. ~10 us even latency-bound.
__global__ __launch_bounds__(256) void indrnn_boundary(
    const float* __restrict__ w,
    const float* __restrict__ h0,
    const float* __restrict__ Bws,
    const float* __restrict__ Cws,
    float* __restrict__ Hstart)       // [NC][BH]
{
    const int i4 = blockIdx.x * 256 + threadIdx.x;   // BH4 threads
    const float4 wv = reinterpret_cast<const float4*>(w)[i4 & (H4 - 1)];

    // A = w^TC = w^32 via 5 squarings
    float4 A = wv;
    #pragma unroll
    for (int k = 0; k < 5; ++k) {
        A.x *= A.x; A.y *= A.y; A.z *= A.z; A.w *= A.w;
    }

    float4 h = reinterpret_cast<const float4*>(h0)[i4];
    for (int c = 0; c < NC; ++c) {
        reinterpret_cast<float4*>(Hstart)[(size_t)c * BH4 + i4] = h;
        const float4 Bv = reinterpret_cast<const float4*>(Bws)[(size_t)c * BH4 + i4];
        const float4 Cv = reinterpret_cast<const float4*>(Cws)[(size_t)c * BH4 + i4];
        h.x = fmaxf(fmaf(A.x, h.x, Bv.x), Cv.x);
        h.y = fmaxf(fmaf(A.y, h.y, Bv.y), Cv.y);
        h.z = fmaxf(fmaf(A.z, h.z, Bv.z), Cv.z);
        h.w = fmaxf(fmaf(A.w, h.w, Bv.w), Cv.w);
    }
}

// Pass 3: per-chunk recurrence from the exact chunk-start h.
__global__ __launch_bounds__(256, 6) void indrnn_run(
    const float* __restrict__ x,
    const float* __restrict__ w,
    const float* __restrict__ Hstart,
    float* __restrict__ out)
{
    const int g  = blockIdx.x * 256 + threadIdx.x;   // NC * BH4 threads
    const int c  = g >> LOG2_BH4;
    const int i4 = g & (BH4 - 1);
    const float4 wv = reinterpret_cast<const float4*>(w)[i4 & (H4 - 1)];

    float4 h = reinterpret_cast<const float4*>(Hstart)[(size_t)c * BH4 + i4];

    const float4* xp = reinterpret_cast<const float4*>(x)   + (size_t)c * TC * BH4 + i4;
    float4*       op = reinterpret_cast<float4*>(out)       + (size_t)c * TC * BH4 + i4;

    float4 buf[W];
    #pragma unroll
    for (int i = 0; i < W; ++i) buf[i] = xp[(size_t)i * BH4];

    for (int t0 = 0; t0 < TC; t0 += W) {
        const int tp = (t0 + W < TC) ? (t0 + W) : 0;
        float4 nbuf[W];
        #pragma unroll
        for (int i = 0; i < W; ++i) nbuf[i] = xp[(size_t)(tp + i) * BH4];

        #pragma unroll
        for (int i = 0; i < W; ++i) {
            h = relu_step(h, wv, buf[i]);
            nt_store4(op + (size_t)(t0 + i) * BH4, h);
        }
        #pragma unroll
        for (int i = 0; i < W; ++i) buf[i] = nbuf[i];
    }
}

extern "C" void kernel_launch(void* const* d_in, const int* in_sizes, int n_in,
                              void* d_out, int out_size, void* d_ws, size_t ws_size,
                              hipStream_t stream) {
    const float* x  = (const float*)d_in[0];
    const float* w  = (const float*)d_in[1];
    const float* h0 = (const float*)d_in[2];
    float* out = (float*)d_out;

    // workspace: Bws + Cws + Hstart, each [NC][BH] floats = 8 MiB -> 24 MiB
    float* Bws    = (float*)d_ws;
    float* Cws    = Bws + (size_t)NC * BH;
    float* Hstart = Cws + (size_t)NC * BH;

    indrnn_compose <<<NC * BH4 / 256, 256, 0, stream>>>(x, w, Bws, Cws);
    indrnn_boundary<<<BH4 / 256,      256, 0, stream>>>(w, h0, Bws, Cws, Hstart);
    indrnn_run     <<<NC * BH4 / 256, 256, 0, stream>>>(x, w, Hstart, out);
}